// Round 1
// 643.193 us; speedup vs baseline: 1.0022x; 1.0022x over previous
//
#include <hip/hip_runtime.h>

// One thread per window, 512 threads/block.
// Layout of samples: [(pixel p)*N + n]*3 + c, p = i*12 + j.
// Consecutive lanes = consecutive windows -> each wave-load is a contiguous
// 768B dwordx3 burst, and all 8 waves of a block walk the SAME pixel sequence
// over 512 adjacent windows => ~6KB instantaneous contiguity per pixel step.
__global__ __launch_bounds__(512) void spa_kernel(
    const float* __restrict__ s1, const float* __restrict__ s2,
    float* __restrict__ out, int N, float scale) {
  const int win = blockIdx.x * 512 + threadIdx.x;

  // P[p]: pooled diff accumulator, p = (i/4)*3 + (j/4). Sum of per-pixel
  // channel-sum differences over the 4x4 pool region; /48 at the end
  // (3 channels * 16 pixels).
  float P[9];
#pragma unroll
  for (int k = 0; k < 9; ++k) P[k] = 0.f;

  if (win < N) {
    const size_t stride = (size_t)N * 3u;  // floats between pixel slabs
    const float* p1 = s1 + (size_t)win * 3u;
    const float* p2 = s2 + (size_t)win * 3u;
#pragma unroll 1  // keep VGPRs bounded: 24 loads in flight per row is plenty
    for (int i = 0; i < 12; ++i) {
      const int pr = (i >> 2) * 3;
#pragma unroll
      for (int j = 0; j < 12; ++j) {
        const float* a = p1 + (size_t)j * stride;
        const float* b = p2 + (size_t)j * stride;
        float d = (a[0] + a[1] + a[2]) - (b[0] + b[1] + b[2]);
        P[pr + (j >> 2)] += d;
      }
      p1 += (size_t)12 * stride;  // advance one pixel row
      p2 += (size_t)12 * stride;
    }
  }

#pragma unroll
  for (int k = 0; k < 9; ++k) P[k] *= (1.0f / 48.0f);

  // 4 directional grads (zero padding), squared sum.
  // win>=N lanes have P=0 -> e=0, safe to compute unconditionally.
  float e = 0.f;
#pragma unroll
  for (int i = 0; i < 3; ++i) {
#pragma unroll
    for (int j = 0; j < 3; ++j) {
      float c = P[i * 3 + j];
      float l = (j > 0) ? P[i * 3 + j - 1] : 0.f;
      float r = (j < 2) ? P[i * 3 + j + 1] : 0.f;
      float u = (i > 0) ? P[(i - 1) * 3 + j] : 0.f;
      float d = (i < 2) ? P[(i + 1) * 3 + j] : 0.f;
      float dl = c - l, dr = c - r, du = c - u, dd = c - d;
      e += dl * dl + dr * dr + du * du + dd * dd;
    }
  }

  // Wave reduce (64 lanes), then block reduce over 8 waves, one atomic/block.
  const int lane = threadIdx.x & 63;
  const int wid = threadIdx.x >> 6;
#pragma unroll
  for (int off = 32; off > 0; off >>= 1) e += __shfl_down(e, off, 64);

  __shared__ float sPart[8];
  if (lane == 0) sPart[wid] = e;
  __syncthreads();
  if (threadIdx.x == 0) {
    float t = 0.f;
#pragma unroll
    for (int w = 0; w < 8; ++w) t += sPart[w];
    atomicAdd(out, t * scale);
  }
}

extern "C" void kernel_launch(void* const* d_in, const int* in_sizes, int n_in,
                              void* d_out, int out_size, void* d_ws, size_t ws_size,
                              hipStream_t stream) {
  const float* s1 = (const float*)d_in[0];
  const float* s2 = (const float*)d_in[1];
  float* out = (float*)d_out;
  int N = in_sizes[0] / (12 * 12 * 3);
  float scale = 1.0f / (9.0f * (float)N);
  hipMemsetAsync(d_out, 0, sizeof(float), stream);
  int blocks = (N + 511) / 512;
  spa_kernel<<<blocks, 512, 0, stream>>>(s1, s2, out, N, scale);
}